// Round 5
// baseline (182.187 us; speedup 1.0000x reference)
//
#include <hip/hip_runtime.h>
#include <hip/hip_bf16.h>
#include <stdint.h>

typedef unsigned int u32;
typedef unsigned short u16;
typedef __attribute__((ext_vector_type(8))) short short8;     // 8 bf16 (MFMA A/B frag)
typedef __attribute__((ext_vector_type(16))) float floatx16;  // 32x32 MFMA C/D frag

#define N_DIM 1024       // ROW*Y_ROW (output features)
#define K_DIM 1024       // COL*Z_COL (input features)
#define M_DIM 16384      // BATCH*SEQ
#define EPW2 68          // epilogue LDS row stride in words (64 fp32 + 4 pad, 16B-aligned)

__device__ __forceinline__ u32 pack4(uint4 v) {
    return (v.x & 0xffu) | ((v.y & 0xffu) << 8) | ((v.z & 0xffu) << 16) | (v.w << 24);
}

__device__ __forceinline__ u16 bf16rne(float f) {
    u32 u = __float_as_uint(f);
    return (u16)((u + 0x7fffu + ((u >> 16) & 1u)) >> 16);
}

// async global->LDS, 16B per lane. LDS dest must be wave-uniform base + lane*16.
__device__ __forceinline__ void load16_lds(const void* g, void* l) {
    __builtin_amdgcn_global_load_lds(
        (const __attribute__((address_space(1))) void*)g,
        (__attribute__((address_space(3))) void*)l, 16, 0, 0);
}

// ---------------------------------------------------------------------------
// build_w: W[n,k] (bf16, row-major [N_DIM][K_DIM], n=r*128+y, k=c*128+z)
//   = d + sum_bit( a*popcnt(Y&Z) + b*Ysum + c*Zsum )
// Uniform runtime detection of uint8 vs int32-widened packed inputs.
// Grid: 256 blocks = (r,c) x z-quarter, 256 threads.
// ---------------------------------------------------------------------------
__global__ __launch_bounds__(256) void build_w(
        const u32* __restrict__ yp, const u32* __restrict__ zp,
        const int* __restrict__ ysum, const int* __restrict__ zsum,
        const float* __restrict__ pa, const float* __restrict__ pb,
        const float* __restrict__ pc, const float* __restrict__ pd,
        __hip_bfloat16* __restrict__ Wb) {
    __shared__ u32 sY[4096];   // [bit][y][t] words (16 KiB)
    __shared__ u32 sZ[1024];   // [bit][zl][t] words (4 KiB)
    __shared__ int sYs[512];
    __shared__ int sZs[128];

    const int tid = threadIdx.x;
    const int rc = blockIdx.x >> 2;
    const int zq = blockIdx.x & 3;
    const int r = rc >> 3, c = rc & 7;
    const int z0 = zq * 32;

    // uniform mode detect (32 logical bytes vs Y_sum[0])
    const uint4 d0 = ((const uint4*)yp)[0], d1 = ((const uint4*)yp)[1];
    const int sdet = __popc(d0.x) + __popc(d0.y) + __popc(d0.z) + __popc(d0.w)
                   + __popc(d1.x) + __popc(d1.y) + __popc(d1.z) + __popc(d1.w);
    const bool widened = (sdet != ysum[0]);

    if (!widened) {
#pragma unroll
        for (int j = 0; j < 4; ++j) {
            const int chunk = tid + j * 256;
            const int f = chunk * 4;                    // logical word id in block
            const int bit = f >> 10, rem = f & 1023;
            const u32 gw = (u32)((bit * 64 + r * 8 + c) * 1024 + rem);
            ((uint4*)sY)[chunk] = *(const uint4*)(yp + gw);
        }
        {
            const int f = tid * 4;
            const int bit = f >> 8;
            const u32 gw = (u32)((bit * 64 + r * 8 + c) * 1024 + z0 * 8 + (f & 255));
            ((uint4*)sZ)[tid] = *(const uint4*)(zp + gw);
        }
    } else {
#pragma unroll
        for (int j = 0; j < 4; ++j) {
            const int chunk = tid + j * 256;
            const int f = chunk * 4;
            const int bit = f >> 10, rem = f & 1023;
            const u32 gw = (u32)((bit * 64 + r * 8 + c) * 1024 + rem);
            uint4 o;
            o.x = pack4(((const uint4*)yp)[gw + 0]);
            o.y = pack4(((const uint4*)yp)[gw + 1]);
            o.z = pack4(((const uint4*)yp)[gw + 2]);
            o.w = pack4(((const uint4*)yp)[gw + 3]);
            ((uint4*)sY)[chunk] = o;
        }
        {
            const int f = tid * 4;
            const int bit = f >> 8;
            const u32 gw = (u32)((bit * 64 + r * 8 + c) * 1024 + z0 * 8 + (f & 255));
            uint4 o;
            o.x = pack4(((const uint4*)zp)[gw + 0]);
            o.y = pack4(((const uint4*)zp)[gw + 1]);
            o.z = pack4(((const uint4*)zp)[gw + 2]);
            o.w = pack4(((const uint4*)zp)[gw + 3]);
            ((uint4*)sZ)[tid] = o;
        }
    }
    for (int j = tid; j < 512; j += 256) {
        const int bit = j >> 7, y = j & 127;
        sYs[j] = ysum[((bit * 8 + r) * 8 + c) * 128 + y];
    }
    if (tid < 128) {
        const int bit = tid >> 5, zl = tid & 31;
        sZs[tid] = zsum[((bit * 8 + r) * 8 + c) * 128 + z0 + zl];
    }
    __syncthreads();

    float av[4], bv[4], cv[4];
#pragma unroll
    for (int bit = 0; bit < 4; ++bit) { av[bit] = pa[bit]; bv[bit] = pb[bit]; cv[bit] = pc[bit]; }
    const float dv = pd[0];

    const int y = tid & 127;
    const int zh = tid >> 7;       // 0/1 -> 16 z each

    u32 yw[4][8];
    float base = dv;
#pragma unroll
    for (int bit = 0; bit < 4; ++bit) {
        const uint4 q0 = ((const uint4*)sY)[bit * 256 + y * 2];
        const uint4 q1 = ((const uint4*)sY)[bit * 256 + y * 2 + 1];
        yw[bit][0] = q0.x; yw[bit][1] = q0.y; yw[bit][2] = q0.z; yw[bit][3] = q0.w;
        yw[bit][4] = q1.x; yw[bit][5] = q1.y; yw[bit][6] = q1.z; yw[bit][7] = q1.w;
        base += bv[bit] * (float)sYs[bit * 128 + y];
    }

    const int m = r * 128 + y;
#pragma unroll
    for (int zl2 = 0; zl2 < 16; ++zl2) {
        const int zl = zh * 16 + zl2;
        float wv = base;
#pragma unroll
        for (int bit = 0; bit < 4; ++bit) {
            const uint4 zw0 = ((const uint4*)sZ)[bit * 64 + zl * 2];
            const uint4 zw1 = ((const uint4*)sZ)[bit * 64 + zl * 2 + 1];
            int p = 0;
            p += __popc(yw[bit][0] & zw0.x);
            p += __popc(yw[bit][1] & zw0.y);
            p += __popc(yw[bit][2] & zw0.z);
            p += __popc(yw[bit][3] & zw0.w);
            p += __popc(yw[bit][4] & zw1.x);
            p += __popc(yw[bit][5] & zw1.y);
            p += __popc(yw[bit][6] & zw1.z);
            p += __popc(yw[bit][7] & zw1.w);
            wv += av[bit] * (float)p + cv[bit] * (float)sZs[bit * 32 + zl];
        }
        const int k = c * 128 + z0 + zl;
        Wb[(size_t)m * K_DIM + k] = __float2bfloat16(wv);
    }
}

// ---------------------------------------------------------------------------
// convert_x: X fp32 [16384][1024] -> bf16 (RNE). 8192 blocks x 256 threads.
// ---------------------------------------------------------------------------
__global__ __launch_bounds__(256) void convert_x(const float4* __restrict__ X,
                                                 ushort4* __restrict__ Xb) {
    const size_t base = (size_t)blockIdx.x * 512;
    const int tid = threadIdx.x;
    const float4 a = X[base + tid];
    const float4 b = X[base + 256 + tid];
    ushort4 oa, ob;
    oa.x = bf16rne(a.x); oa.y = bf16rne(a.y); oa.z = bf16rne(a.z); oa.w = bf16rne(a.w);
    ob.x = bf16rne(b.x); ob.y = bf16rne(b.y); ob.z = bf16rne(b.z); ob.w = bf16rne(b.w);
    Xb[base + tid] = oa;
    Xb[base + 256 + tid] = ob;
}

// ---------------------------------------------------------------------------
// gemm_bias: out[M,N] = Xb[M,K] * Wb[N,K]^T + bias[N]  (32x32x16 bf16 MFMA)
// Block tile 128(M) x 128(N), BK=64, 256 threads = 4 waves (2Mx2N) of 64x64,
// each wave = 2x2 tiles of 32x32. Staging via global_load_lds (16B/lane),
// XOR-swizzled LDS: chunk (row, kc) stored at index row*8 + (kc ^ (row&7)).
// Grid dim3(128, 8) = 1024 blocks = 4 blocks/CU (2x the drain overlap of R4).
// ---------------------------------------------------------------------------
__global__ __launch_bounds__(256, 4) void gemm_bias(
        const u16* __restrict__ Xb, const u16* __restrict__ Wb,
        const float* __restrict__ bias, float* __restrict__ out) {
    __shared__ __align__(16) char lds[34816];   // main 32KB; epilogue 4x8704B
    char* As = lds;              // 16 KB: 128 rows x 128 B (swizzled)
    char* Bs = lds + 16384;      // 16 KB: 128 rows x 128 B (swizzled)

    const int tid = threadIdx.x;
    const int lane = tid & 63;
    const int w = tid >> 6;          // wave 0..3
    const int wr = w >> 1;           // 0..1 (M)
    const int wc = w & 1;            // 0..1 (N)
    const int mtile = blockIdx.x;    // 0..127  (fast dim -> XCD = mtile%8)
    const int ntile = blockIdx.y;    // 0..7
    const int m0 = mtile * 128, n0 = ntile * 128;

    // staging lane decomposition: 64 lanes cover 8 rows x 8 chunks (1KB/instr)
    const int lrow = lane >> 3;                  // 0..7
    const int lkc  = (lane & 7) ^ lrow;          // swizzled source 16B-chunk
    // fragment lanes (32x32x16: A[m=lane&31][k=(lane>>5)*8+j])
    const int fn = lane & 31;
    const int fh = lane >> 5;

    floatx16 acc[2][2] = {};

    for (int kt = 0; kt < K_DIM / 64; ++kt) {
        __syncthreads();   // previous tile's readers done
        // A: 1024 chunks (128 rows x 8) -> 16 wave-groups, 4 instr/thread
#pragma unroll
        for (int j = 0; j < 4; ++j) {
            const int cw = j * 4 + w;                 // chunk-group 0..15
            const int row = cw * 8 + lrow;            // 0..127
            load16_lds(Xb + (size_t)(m0 + row) * K_DIM + kt * 64 + lkc * 8,
                       As + cw * 1024 + lane * 16);
        }
        // B: 1024 chunks (128 rows x 8), 4 instr/thread
#pragma unroll
        for (int j = 0; j < 4; ++j) {
            const int cw = j * 4 + w;
            const int row = cw * 8 + lrow;
            load16_lds(Wb + (size_t)(n0 + row) * K_DIM + kt * 64 + lkc * 8,
                       Bs + cw * 1024 + lane * 16);
        }
        __syncthreads();   // vmcnt(0) drain + barrier

#pragma unroll
        for (int ks = 0; ks < 4; ++ks) {          // K=16 per step
            const int chunk = ks * 2 + fh;        // 16B chunk within row
            short8 af[2], bf[2];
#pragma unroll
            for (int mi = 0; mi < 2; ++mi) {
                const int row = wr * 64 + mi * 32 + fn;
                af[mi] = *(const short8*)(As + row * 128 + ((chunk ^ (row & 7)) * 16));
            }
#pragma unroll
            for (int ni = 0; ni < 2; ++ni) {
                const int row = wc * 64 + ni * 32 + fn;
                bf[ni] = *(const short8*)(Bs + row * 128 + ((chunk ^ (row & 7)) * 16));
            }
#pragma unroll
            for (int mi = 0; mi < 2; ++mi)
#pragma unroll
                for (int ni = 0; ni < 2; ++ni)
                    acc[mi][ni] = __builtin_amdgcn_mfma_f32_32x32x16_bf16(
                        af[mi], bf[ni], acc[mi][ni], 0, 0, 0);
        }
    }

    // -----------------------------------------------------------------------
    // Epilogue. 32x32 C/D layout: col=lane&31, row=(reg&3)+8*(reg>>2)+4*(lane>>5).
    // Per-wave private LDS slice (32 x EPW2 fp32 = 8704B): transpose to
    // row-major, store float4 (256B contiguous per 16-lane group).
    // -----------------------------------------------------------------------
    float bias_r[2];
#pragma unroll
    for (int ni = 0; ni < 2; ++ni)
        bias_r[ni] = bias[n0 + wc * 64 + ni * 32 + fn];

    __syncthreads();   // all waves done with As/Bs tiles
    float* ep = (float*)lds + w * (32 * EPW2);
    const int gm0 = m0 + wr * 64;
    const int gn0 = n0 + wc * 64;

#pragma unroll
    for (int mi = 0; mi < 2; ++mi) {
#pragma unroll
        for (int ni = 0; ni < 2; ++ni)
#pragma unroll
            for (int reg = 0; reg < 16; ++reg) {
                const int rl = (reg & 3) + 8 * (reg >> 2) + 4 * fh;
                ep[rl * EPW2 + ni * 32 + fn] = acc[mi][ni][reg] + bias_r[ni];
            }
#pragma unroll
        for (int t = 0; t < 8; ++t) {
            const int flat = t * 64 + lane;          // 0..511
            const int lr = flat >> 4;                // local row 0..31
            const int c4 = flat & 15;                // float4 col
            const float4 v = *(const float4*)(ep + lr * EPW2 + c4 * 4);
            *(float4*)(out + (size_t)(gm0 + mi * 32 + lr) * N_DIM + gn0 + c4 * 4) = v;
        }
        // wave-private slice; per-wave DS ordering makes the mi=1 rewrite safe
    }
}

// ---------------------------------------------------------------------------
extern "C" void kernel_launch(void* const* d_in, const int* in_sizes, int n_in,
                              void* d_out, int out_size, void* d_ws, size_t ws_size,
                              hipStream_t stream) {
    const float* X   = (const float*)d_in[0];
    const u32*   Yp  = (const u32*)d_in[1];
    const u32*   Zp  = (const u32*)d_in[2];
    const int*   Ys  = (const int*)d_in[3];
    const int*   Zs  = (const int*)d_in[4];
    const float* pa  = (const float*)d_in[5];
    const float* pb  = (const float*)d_in[6];
    const float* pc  = (const float*)d_in[7];
    const float* pd  = (const float*)d_in[8];
    const float* bias = (const float*)d_in[9];
    float* out = (float*)d_out;

    char* ws = (char*)d_ws;
    __hip_bfloat16* Wb = (__hip_bfloat16*)ws;                 // 2 MiB
    u16*            Xb = (u16*)(ws + (2u << 20));             // 32 MiB

    build_w<<<256, 256, 0, stream>>>(Yp, Zp, Ys, Zs, pa, pb, pc, pd, Wb);
    convert_x<<<8192, 256, 0, stream>>>((const float4*)X, (ushort4*)Xb);
    gemm_bias<<<dim3(128, 8), 256, 0, stream>>>(Xb, (const u16*)Wb, bias, out);
}

// Round 6
// 173.489 us; speedup vs baseline: 1.0501x; 1.0501x over previous
//
#include <hip/hip_runtime.h>
#include <hip/hip_bf16.h>
#include <stdint.h>

typedef unsigned int u32;
typedef unsigned short u16;
typedef __attribute__((ext_vector_type(8))) short short8;   // 8 bf16 (MFMA A/B frag)
typedef __attribute__((ext_vector_type(4))) float floatx4;  // 16x16 MFMA C/D frag

#define N_DIM 1024       // ROW*Y_ROW (output features)
#define K_DIM 1024       // COL*Z_COL (input features)
#define M_DIM 16384      // BATCH*SEQ
#define EPW  68          // epilogue LDS row stride in words (64 fp32 + 4 pad)

__device__ __forceinline__ u32 pack4(uint4 v) {
    return (v.x & 0xffu) | ((v.y & 0xffu) << 8) | ((v.z & 0xffu) << 16) | (v.w << 24);
}

__device__ __forceinline__ u16 bf16rne(float f) {
    u32 u = __float_as_uint(f);
    return (u16)((u + 0x7fffu + ((u >> 16) & 1u)) >> 16);
}

// async global->LDS, 16B per lane. LDS dest must be wave-uniform base + lane*16.
__device__ __forceinline__ void load16_lds(const void* g, void* l) {
    __builtin_amdgcn_global_load_lds(
        (const __attribute__((address_space(1))) void*)g,
        (__attribute__((address_space(3))) void*)l, 16, 0, 0);
}

// ---------------------------------------------------------------------------
// build_w: W[n,k] (bf16, row-major [N_DIM][K_DIM], n=r*128+y, k=c*128+z)
//   = d + sum_bit( a*popcnt(Y&Z) + b*Ysum + c*Zsum )
// Uniform runtime detection of uint8 vs int32-widened packed inputs.
// Grid: 256 blocks = (r,c) x z-quarter, 256 threads.
// ---------------------------------------------------------------------------
__global__ __launch_bounds__(256) void build_w(
        const u32* __restrict__ yp, const u32* __restrict__ zp,
        const int* __restrict__ ysum, const int* __restrict__ zsum,
        const float* __restrict__ pa, const float* __restrict__ pb,
        const float* __restrict__ pc, const float* __restrict__ pd,
        __hip_bfloat16* __restrict__ Wb) {
    __shared__ u32 sY[4096];   // [bit][y][t] words (16 KiB)
    __shared__ u32 sZ[1024];   // [bit][zl][t] words (4 KiB)
    __shared__ int sYs[512];
    __shared__ int sZs[128];

    const int tid = threadIdx.x;
    const int rc = blockIdx.x >> 2;
    const int zq = blockIdx.x & 3;
    const int r = rc >> 3, c = rc & 7;
    const int z0 = zq * 32;

    // uniform mode detect (32 logical bytes vs Y_sum[0])
    const uint4 d0 = ((const uint4*)yp)[0], d1 = ((const uint4*)yp)[1];
    const int sdet = __popc(d0.x) + __popc(d0.y) + __popc(d0.z) + __popc(d0.w)
                   + __popc(d1.x) + __popc(d1.y) + __popc(d1.z) + __popc(d1.w);
    const bool widened = (sdet != ysum[0]);

    if (!widened) {
#pragma unroll
        for (int j = 0; j < 4; ++j) {
            const int chunk = tid + j * 256;
            const int f = chunk * 4;                    // logical word id in block
            const int bit = f >> 10, rem = f & 1023;
            const u32 gw = (u32)((bit * 64 + r * 8 + c) * 1024 + rem);
            ((uint4*)sY)[chunk] = *(const uint4*)(yp + gw);
        }
        {
            const int f = tid * 4;
            const int bit = f >> 8;
            const u32 gw = (u32)((bit * 64 + r * 8 + c) * 1024 + z0 * 8 + (f & 255));
            ((uint4*)sZ)[tid] = *(const uint4*)(zp + gw);
        }
    } else {
#pragma unroll
        for (int j = 0; j < 4; ++j) {
            const int chunk = tid + j * 256;
            const int f = chunk * 4;
            const int bit = f >> 10, rem = f & 1023;
            const u32 gw = (u32)((bit * 64 + r * 8 + c) * 1024 + rem);
            uint4 o;
            o.x = pack4(((const uint4*)yp)[gw + 0]);
            o.y = pack4(((const uint4*)yp)[gw + 1]);
            o.z = pack4(((const uint4*)yp)[gw + 2]);
            o.w = pack4(((const uint4*)yp)[gw + 3]);
            ((uint4*)sY)[chunk] = o;
        }
        {
            const int f = tid * 4;
            const int bit = f >> 8;
            const u32 gw = (u32)((bit * 64 + r * 8 + c) * 1024 + z0 * 8 + (f & 255));
            uint4 o;
            o.x = pack4(((const uint4*)zp)[gw + 0]);
            o.y = pack4(((const uint4*)zp)[gw + 1]);
            o.z = pack4(((const uint4*)zp)[gw + 2]);
            o.w = pack4(((const uint4*)zp)[gw + 3]);
            ((uint4*)sZ)[tid] = o;
        }
    }
    for (int j = tid; j < 512; j += 256) {
        const int bit = j >> 7, y = j & 127;
        sYs[j] = ysum[((bit * 8 + r) * 8 + c) * 128 + y];
    }
    if (tid < 128) {
        const int bit = tid >> 5, zl = tid & 31;
        sZs[tid] = zsum[((bit * 8 + r) * 8 + c) * 128 + z0 + zl];
    }
    __syncthreads();

    float av[4], bv[4], cv[4];
#pragma unroll
    for (int bit = 0; bit < 4; ++bit) { av[bit] = pa[bit]; bv[bit] = pb[bit]; cv[bit] = pc[bit]; }
    const float dv = pd[0];

    const int y = tid & 127;
    const int zh = tid >> 7;       // 0/1 -> 16 z each

    u32 yw[4][8];
    float base = dv;
#pragma unroll
    for (int bit = 0; bit < 4; ++bit) {
        const uint4 q0 = ((const uint4*)sY)[bit * 256 + y * 2];
        const uint4 q1 = ((const uint4*)sY)[bit * 256 + y * 2 + 1];
        yw[bit][0] = q0.x; yw[bit][1] = q0.y; yw[bit][2] = q0.z; yw[bit][3] = q0.w;
        yw[bit][4] = q1.x; yw[bit][5] = q1.y; yw[bit][6] = q1.z; yw[bit][7] = q1.w;
        base += bv[bit] * (float)sYs[bit * 128 + y];
    }

    const int m = r * 128 + y;
#pragma unroll
    for (int zl2 = 0; zl2 < 16; ++zl2) {
        const int zl = zh * 16 + zl2;
        float wv = base;
#pragma unroll
        for (int bit = 0; bit < 4; ++bit) {
            const uint4 zw0 = ((const uint4*)sZ)[bit * 64 + zl * 2];
            const uint4 zw1 = ((const uint4*)sZ)[bit * 64 + zl * 2 + 1];
            int p = 0;
            p += __popc(yw[bit][0] & zw0.x);
            p += __popc(yw[bit][1] & zw0.y);
            p += __popc(yw[bit][2] & zw0.z);
            p += __popc(yw[bit][3] & zw0.w);
            p += __popc(yw[bit][4] & zw1.x);
            p += __popc(yw[bit][5] & zw1.y);
            p += __popc(yw[bit][6] & zw1.z);
            p += __popc(yw[bit][7] & zw1.w);
            wv += av[bit] * (float)p + cv[bit] * (float)sZs[bit * 32 + zl];
        }
        const int k = c * 128 + z0 + zl;
        Wb[(size_t)m * K_DIM + k] = __float2bfloat16(wv);
    }
}

// ---------------------------------------------------------------------------
// convert_x: X fp32 [16384][1024] -> bf16 (RNE). 8192 blocks x 256 threads.
// ---------------------------------------------------------------------------
__global__ __launch_bounds__(256) void convert_x(const float4* __restrict__ X,
                                                 ushort4* __restrict__ Xb) {
    const size_t base = (size_t)blockIdx.x * 512;
    const int tid = threadIdx.x;
    const float4 a = X[base + tid];
    const float4 b = X[base + 256 + tid];
    ushort4 oa, ob;
    oa.x = bf16rne(a.x); oa.y = bf16rne(a.y); oa.z = bf16rne(a.z); oa.w = bf16rne(a.w);
    ob.x = bf16rne(b.x); ob.y = bf16rne(b.y); ob.z = bf16rne(b.z); ob.w = bf16rne(b.w);
    Xb[base + tid] = oa;
    Xb[base + 256 + tid] = ob;
}

// ---------------------------------------------------------------------------
// gemm_bias: out[M,N] = Xb[M,K] * Wb[N,K]^T + bias[N]  (16x16x32 bf16 MFMA)
// Block tile 128(M) x 128(N), BK=64, 256 threads = 4 waves (2Mx2N) of 64x64,
// each wave = 4x4 tiles of 16x16 (R4's conflict-free fragment geometry).
// Staging via global_load_lds (16B/lane), XOR-swizzled LDS layout:
// chunk (row, kc) stored at slot kc ^ (row&7) within the row.
// Grid dim3(128, 8) = 1024 blocks, mtile-fast -> XCD = mtile%8 for L2 reuse.
// LDS exactly 32 KiB -> up to 4-5 blocks/CU for barrier-drain overlap.
// ---------------------------------------------------------------------------
__global__ __launch_bounds__(256, 4) void gemm_bias(
        const u16* __restrict__ Xb, const u16* __restrict__ Wb,
        const float* __restrict__ bias, float* __restrict__ out) {
    __shared__ __align__(16) char lds[32768];
    char* As = lds;              // 16 KB: 128 rows x 128 B (swizzled)
    char* Bs = lds + 16384;      // 16 KB: 128 rows x 128 B (swizzled)

    const int tid = threadIdx.x;
    const int lane = tid & 63;
    const int w = tid >> 6;          // wave 0..3
    const int wr = w >> 1;           // 0..1 (M)
    const int wc = w & 1;            // 0..1 (N)
    const int mtile = blockIdx.x;    // 0..127  (fast dim -> XCD = mtile%8)
    const int ntile = blockIdx.y;    // 0..7
    const int m0 = mtile * 128, n0 = ntile * 128;

    // staging lane decomposition: 64 lanes cover 8 rows x 8 chunks (1KB/instr)
    const int lrow = lane >> 3;                  // 0..7
    const int lkc  = (lane & 7) ^ lrow;          // swizzled source 16B-chunk
    // fragment lanes (16x16x32: A[m=lane&15][k=(lane>>4)*8+j])
    const int fm = lane & 15, fq = lane >> 4;
    const int cx0 = ((0 + fq) ^ (fm & 7)) * 16;  // kk=0 swizzled byte col
    const int cx1 = ((4 + fq) ^ (fm & 7)) * 16;  // kk=1

    floatx4 acc[4][4] = {};

    for (int kt = 0; kt < K_DIM / 64; ++kt) {
        __syncthreads();   // previous tile's readers done
        // A: 1024 chunks (128 rows x 8), 4 instr/thread
#pragma unroll
        for (int j = 0; j < 4; ++j) {
            const int cw = j * 4 + w;                 // chunk-group 0..15
            const int row = cw * 8 + lrow;            // 0..127
            load16_lds(Xb + (size_t)(m0 + row) * K_DIM + kt * 64 + lkc * 8,
                       As + cw * 1024 + lane * 16);
        }
        // B: 1024 chunks (128 rows x 8), 4 instr/thread
#pragma unroll
        for (int j = 0; j < 4; ++j) {
            const int cw = j * 4 + w;
            const int row = cw * 8 + lrow;
            load16_lds(Wb + (size_t)(n0 + row) * K_DIM + kt * 64 + lkc * 8,
                       Bs + cw * 1024 + lane * 16);
        }
        __syncthreads();   // vmcnt(0) drain + barrier

#pragma unroll
        for (int kk = 0; kk < 2; ++kk) {
            const int cx = kk ? cx1 : cx0;
            short8 afr[4], bfr[4];
#pragma unroll
            for (int mi = 0; mi < 4; ++mi)
                afr[mi] = *(const short8*)(As + (wr * 64 + mi * 16 + fm) * 128 + cx);
#pragma unroll
            for (int ni = 0; ni < 4; ++ni)
                bfr[ni] = *(const short8*)(Bs + (wc * 64 + ni * 16 + fm) * 128 + cx);
#pragma unroll
            for (int mi = 0; mi < 4; ++mi)
#pragma unroll
                for (int ni = 0; ni < 4; ++ni)
                    acc[mi][ni] = __builtin_amdgcn_mfma_f32_16x16x32_bf16(
                        afr[mi], bfr[ni], acc[mi][ni], 0, 0, 0);
        }
    }

    // -----------------------------------------------------------------------
    // Epilogue: D layout col(N)=lane&15, row(M)=(lane>>4)*4+reg.
    // Per-wave private LDS slice (16 x EPW fp32 = 4352 B): transpose to
    // row-major, store float4 (256 B contiguous per 16-lane group).
    // -----------------------------------------------------------------------
    float bias_r[4];
#pragma unroll
    for (int ni = 0; ni < 4; ++ni)
        bias_r[ni] = bias[n0 + wc * 64 + ni * 16 + fm];

    __syncthreads();   // all waves done with As/Bs tiles
    float* ep = (float*)lds + w * (16 * EPW);   // 4 waves x 4352 B = 17.4 KB
    const int gm0 = m0 + wr * 64;
    const int gn0 = n0 + wc * 64;

#pragma unroll
    for (int mi = 0; mi < 4; ++mi) {
#pragma unroll
        for (int ni = 0; ni < 4; ++ni)
#pragma unroll
            for (int reg = 0; reg < 4; ++reg)
                ep[(fq * 4 + reg) * EPW + ni * 16 + fm] = acc[mi][ni][reg] + bias_r[ni];
#pragma unroll
        for (int t = 0; t < 4; ++t) {
            const int lr = t * 4 + fq;               // local row 0..15
            const float4 v = *(const float4*)(ep + lr * EPW + fm * 4);
            *(float4*)(out + (size_t)(gm0 + mi * 16 + lr) * N_DIM + gn0 + fm * 4) = v;
        }
        // wave-private slice; per-wave DS ordering makes the rewrite safe
    }
}

// ---------------------------------------------------------------------------
extern "C" void kernel_launch(void* const* d_in, const int* in_sizes, int n_in,
                              void* d_out, int out_size, void* d_ws, size_t ws_size,
                              hipStream_t stream) {
    const float* X   = (const float*)d_in[0];
    const u32*   Yp  = (const u32*)d_in[1];
    const u32*   Zp  = (const u32*)d_in[2];
    const int*   Ys  = (const int*)d_in[3];
    const int*   Zs  = (const int*)d_in[4];
    const float* pa  = (const float*)d_in[5];
    const float* pb  = (const float*)d_in[6];
    const float* pc  = (const float*)d_in[7];
    const float* pd  = (const float*)d_in[8];
    const float* bias = (const float*)d_in[9];
    float* out = (float*)d_out;

    char* ws = (char*)d_ws;
    __hip_bfloat16* Wb = (__hip_bfloat16*)ws;                 // 2 MiB
    u16*            Xb = (u16*)(ws + (2u << 20));             // 32 MiB

    build_w<<<256, 256, 0, stream>>>(Yp, Zp, Ys, Zs, pa, pb, pc, pd, Wb);
    convert_x<<<8192, 256, 0, stream>>>((const float4*)X, (ushort4*)Xb);
    gemm_bias<<<dim3(128, 8), 256, 0, stream>>>(Xb, (const u16*)Wb, bias, out);
}